// Round 13
// baseline (259.664 us; speedup 1.0000x reference)
//
#include <hip/hip_runtime.h>

typedef unsigned short u16;
typedef unsigned int u32;
typedef unsigned long long u64;
typedef __bf16 bf16x8 __attribute__((ext_vector_type(8)));
typedef float f32x4 __attribute__((ext_vector_type(4)));

#define HH  56
#define WW  56
#define HW  3136      // 56*56
#define CC  256
#define NB  8
#define CKP 2048      // c*7 padded to c*8: channel j's taps = cols j*8..j*8+7
#define KS1 4         // split-K factor GEMM1 (49 iters -> 12/12/12/13)

// round-to-nearest-even fp32 -> bf16 (bit pattern) — for non-hot paths
__device__ __forceinline__ u16 f2bf(float f) {
  unsigned int u = __float_as_uint(f);
  u += 0x7fffu + ((u >> 16) & 1u);
  return (u16)(u >> 16);
}
__device__ __forceinline__ float bf2f(u16 v) {
  return __uint_as_float((unsigned)v << 16);
}

// async global->LDS DMA, 16B per lane; dest = wave-uniform base + lane*16
__device__ __forceinline__ void lds_load16(const void* g, void* l) {
  __builtin_amdgcn_global_load_lds(
      (const __attribute__((address_space(1))) void*)g,
      (__attribute__((address_space(3))) void*)l, 16, 0, 0);
}

// ---------------------------------------------------------------------------
// pass1 (R18-exact): t1b = bf16(p1w * x), xb = bf16(x).  XCD-pinned.
// grid = NB * 784 = 6272
// ---------------------------------------------------------------------------
__global__ void pass1(const float* __restrict__ x, const float* __restrict__ p1w,
                      u16* __restrict__ t1b, u16* __restrict__ xb) {
  const int bi = blockIdx.x;
  const int nb = bi & 7;
  const int inner = bi >> 3;                     // 0..783
  const int cw = inner * 256 + threadIdx.x;      // index into CC*HW/4 (p1w)
  const int i  = nb * (CC * HW / 4) + cw;        // global float4 index
  float4 xv = ((const float4*)x)[i];
  float4 wv = ((const float4*)p1w)[cw];
  uint2 xo = make_uint2((unsigned)f2bf(xv.x) | ((unsigned)f2bf(xv.y) << 16),
                        (unsigned)f2bf(xv.z) | ((unsigned)f2bf(xv.w) << 16));
  ((uint2*)xb)[i] = xo;
  uint2 to = make_uint2((unsigned)f2bf(xv.x * wv.x) | ((unsigned)f2bf(xv.y * wv.y) << 16),
                        (unsigned)f2bf(xv.z * wv.z) | ((unsigned)f2bf(xv.w * wv.w) << 16));
  ((uint2*)t1b)[i] = to;
}

// ---------------------------------------------------------------------------
// gemm1f (R18-exact): R13 structure (4 blocks/CU; VGPR <=128 — no prefetch
// register sets, proven R11/R17) + dead wrap-check removed.
// 2-barrier schedule, select-only B-gen, XCD-pinned flat grid.
//   B rows j*8+k (k<7) = masked taps of t2[j]; row j*8+7 = t1[j] (G-row).
// grid = 1024 flat
// ---------------------------------------------------------------------------
__global__ __launch_bounds__(256)
void gemm1f(const u16* __restrict__ A, const u16* __restrict__ t1b,
            float* __restrict__ Cp) {
  __shared__ u16 As[128 * 64];
  __shared__ u16 Bs[128 * 64];

  const int bi = blockIdx.x;
  const int nb = bi & 7;
  const int r  = bi >> 3;          // 0..127
  const int ks = r & 3;
  const int r2 = r >> 2;           // 0..31
  const int m0b = r2 & 1;
  const int n0b = r2 >> 1;         // 0..15

  const int it0 = 49 * ks / KS1, it1 = 49 * (ks + 1) / KS1;
  const u16* Ab  = A   + (long)nb * CC * HW;
  const u16* t1n = t1b + (long)nb * CC * HW;
  const int m0 = m0b * 128, n0 = n0b * 128;
  const int jb = n0b * 16;                        // first channel of tile
  const int t = threadIdx.x;
  const int lane = t & 63, wave = t >> 6;
  const int wm = wave & 1, wn = wave >> 1;        // 2x2 waves, 64x64 each
  const int lm = lane & 15, quad = lane >> 4;

  // B-gen mapping
  const int jl = (t >> 3) & 15, pc = t & 7, hf = t >> 7;   // hf wave-uniform
  const int j  = jb + jl;
  const int jm = (j + CC - 1) & (CC - 1);
  const u16* arow = t1n + (long)j  * HW;
  const u16* wrow = t1n + (long)jm * HW;

  f32x4 acc[4][4];
#pragma unroll
  for (int a = 0; a < 4; ++a)
#pragma unroll
    for (int b = 0; b < 4; ++b) acc[a][b] = (f32x4)0.0f;

  // A staging geometry: 1024 chunks of 16B, 4 per thread, XOR swizzle
  int rowc[4], colc[4];
#pragma unroll
  for (int ci = 0; ci < 4; ++ci) {
    int c = t + ci * 256;
    rowc[ci] = c >> 3;
    colc[ci] = ((c & 7) ^ (rowc[ci] & 7)) * 8;
  }

  for (int it = it0; it < it1; ++it) {
    const int k0 = it * 64;
#pragma unroll
    for (int ci = 0; ci < 4; ++ci)
      lds_load16(Ab + (long)(m0 + rowc[ci]) * HW + k0 + colc[ci],
                 &As[(t + ci * 256) * 8]);

    // ---- B-gen: 8 p-values (p8..p8+7), rows jl*8+k. Pure u16 selects. ----
    {
      const int p8 = k0 + pc * 8;
      __attribute__((aligned(16))) u16 Ar[8];
      __attribute__((aligned(16))) u16 Wd[24];     // window = flat [p8-8, p8+16)
      *(uint4*)Ar = *(const uint4*)&arow[p8];
#pragma unroll
      for (int L = 0; L < 3; ++L) {
        int ad = p8 - 8 + L * 8;
        ad = ad < 0 ? 0 : (ad > HW - 8 ? HW - 8 : ad);  // garbage only at masked idx
        *(uint4*)&Wd[L * 8] = *(const uint4*)&wrow[ad];
      }
      // w0t = 8*((it+pc) mod 7) in {0,8,...,48}; w0t+e <= 55 -> NO wrap.
      const int w0t = p8 % 56;
      if (hf == 0) {                           // k = 0..3
#pragma unroll
        for (int k = 0; k < 4; ++k) {
          __attribute__((aligned(16))) u16 v[8];
#pragma unroll
          for (int e = 0; e < 8; ++e)
            v[e] = ((unsigned)(w0t + e + k - 3) < 56u) ? Wd[e + k + 5] : (u16)0;
          *(uint4*)&Bs[(jl * 8 + k) * 64 + (pc ^ k) * 8] = *(const uint4*)v;
        }
      } else {                                 // k = 4..6 + G-row (slot 7)
#pragma unroll
        for (int k = 4; k < 7; ++k) {
          __attribute__((aligned(16))) u16 v[8];
#pragma unroll
          for (int e = 0; e < 8; ++e)
            v[e] = ((unsigned)(w0t + e + k - 3) < 56u) ? Wd[e + k + 5] : (u16)0;
          *(uint4*)&Bs[(jl * 8 + k) * 64 + (pc ^ k) * 8] = *(const uint4*)v;
        }
        // slot 7 = t1[j] row -> produces G[i][j] in output col j*8+7
        *(uint4*)&Bs[(jl * 8 + 7) * 64 + (pc ^ 7) * 8] = *(const uint4*)Ar;
      }
    }
    __syncthreads();
#pragma unroll
    for (int kk = 0; kk < 2; ++kk) {
      const int phys = ((kk * 4 + quad) ^ (lm & 7)) * 8;
      bf16x8 af[4], bv[4];
#pragma unroll
      for (int mi = 0; mi < 4; ++mi)
        af[mi] = *(const bf16x8*)&As[(wm * 64 + mi * 16 + lm) * 64 + phys];
#pragma unroll
      for (int ni = 0; ni < 4; ++ni)
        bv[ni] = *(const bf16x8*)&Bs[(wn * 64 + ni * 16 + lm) * 64 + phys];
#pragma unroll
      for (int mi = 0; mi < 4; ++mi)
#pragma unroll
        for (int ni = 0; ni < 4; ++ni)
          acc[mi][ni] = __builtin_amdgcn_mfma_f32_16x16x32_bf16(
              af[mi], bv[ni], acc[mi][ni], 0, 0, 0);
    }
    __syncthreads();
  }

  // fp32 partial store; C/D layout: col = lane&15, row = quad*4 + reg
  float* Cb = Cp + ((long)ks * NB + nb) * (long)CC * CKP;
#pragma unroll
  for (int mi = 0; mi < 4; ++mi)
#pragma unroll
    for (int ni = 0; ni < 4; ++ni) {
      int rb = m0 + wm * 64 + mi * 16 + quad * 4;
      int cg = n0 + wn * 64 + ni * 16 + lm;
#pragma unroll
      for (int r4 = 0; r4 < 4; ++r4)
        Cb[(long)(rb + r4) * CKP + cg] = acc[mi][ni][r4];
    }
}

// ---------------------------------------------------------------------------
// reduce1 (R18-exact): XCD-pinned.  Sums KS1 partials, t7[jk]=(G-H_k)/56,
// S7 in slot 7.  grid = NB * 256 = 2048
// ---------------------------------------------------------------------------
__global__ void reduce1(const float* __restrict__ p1, u16* __restrict__ t7) {
  const int bi = blockIdx.x;
  const int nb = bi & 7;
  const int gg = (bi >> 3) * 256 + threadIdx.x;   // j-group within batch
  const long S = (long)NB * CC * CKP;             // elements per partial
  const long base = (long)nb * CC * CKP + (long)gg * 8;
  float a[8];
#pragma unroll
  for (int e = 0; e < 8; ++e) a[e] = 0.0f;
#pragma unroll
  for (int ks = 0; ks < KS1; ++ks) {
    float4 lo = *(const float4*)&p1[ks * S + base];
    float4 hi = *(const float4*)&p1[ks * S + base + 4];
    a[0] += lo.x; a[1] += lo.y; a[2] += lo.z; a[3] += lo.w;
    a[4] += hi.x; a[5] += hi.y; a[6] += hi.z; a[7] += hi.w;
  }
  const float s = 1.0f / 56.0f;
  const float G = a[7];
  __attribute__((aligned(16))) u16 o[8];
  float s7 = 0.0f;
#pragma unroll
  for (int k = 0; k < 7; ++k) {
    float v = (G - a[k]) * s;
    s7 += v;
    o[k] = f2bf(v);
  }
  o[7] = f2bf(s7);
  *(uint4*)&t7[base] = *(const uint4*)o;
}

// ---------------------------------------------------------------------------
// gemm2f (R21, A-DIRECT): fused NT GEMM, 128x64 tile, BK=64, XCD-pinned.
//   out[i][p] = s2 * ( sum_{j,k<7} t7[i][jk]*tap[j,k,p]  +  S7[i][j]*xb[j][p] )
// A-tile LDS staging DELETED: each MFMA A-fragment is 8 contiguous bf16
// consumed by one lane, so it's loaded straight from t7 (L2-resident,
// 1 MB/batch, shared by 49 blocks) as per-lane global_load_dwordx4 into
// E/O register sets, prefetched one iteration ahead inside the MFMA phase
// (R16-proven placement — full-region cover before the bar_b drain).
// Removes the DMA's LDS-write traffic AND 8 of 12 MFMA-phase ds_read_b128
// (the measured LDS-pipe wall).  LDS 45.5 KB -> 13.6 KB.  B side unchanged
// (funnel-shift BGEN, R19).  grid = 784 flat
// ---------------------------------------------------------------------------
__global__ __launch_bounds__(256)
void gemm2f(const u16* __restrict__ A, const u16* __restrict__ xb,
            const u16* __restrict__ t1b, float* __restrict__ out) {
  __shared__ u16 Bs[64 * 64];                     //  8 KB
  // [8 pad][8ch][2row][56][8 pad] = 912 u16 each
  __shared__ __attribute__((aligned(16))) u16 Rs0[912], Rs1[912];
  __shared__ __attribute__((aligned(16))) u16 Xs0[512], Xs1[512]; // [8ch][64]

  // flat block index -> (nb | m0b | n0b), nb fastest => XCD-pinned
  const int bi = blockIdx.x;
  const int nb = bi & 7;
  const int r  = bi >> 3;          // 0..97
  const int m0b = r & 1;
  const int n0b = r >> 1;          // 0..48

  const u16* Ab  = A   + (long)nb * CC * CKP;
  const u16* xbn = xb  + (long)nb * CC * HW;
  const u16* t1n = t1b + (long)nb * CC * HW;
  const int m0 = m0b * 128, n0 = n0b * 64;
  const int t = threadIdx.x;
  const int lane = t & 63, wave = t >> 6;
  const int wm = wave & 1, wn = wave >> 1;        // 2(m) x 2(n of 32)
  const int lm = lane & 15, quad = lane >> 4;

  // A-direct row pointers: aRowP[mi] -> t7 row (m0+wm*64+mi*16+lm), col quad*8
  const u16* aRowP[4];
#pragma unroll
  for (int mi = 0; mi < 4; ++mi)
    aRowP[mi] = Ab + (long)(m0 + wm * 64 + mi * 16 + lm) * CKP + quad * 8;

  // B-gen read mapping: pr = p-row, jg -> 2 channels per thread per iter
  const int pr = t & 63, jg = t >> 6;
  const int p  = n0 + pr;
  const int h  = p / WW, w = p - h * WW;
  const int w2 = (w + 1) % WW;                    // roll -1 on w
  const int swz = pr & 7;
  const int h_lo = n0 / WW;
  const int slot = h - h_lo;                      // 0 or 1 (64 p span 2 rows)

  // iter-invariant window geometry: channel jj window = Rs u16s [sA, sA+6]
  // (channel jj=1 offset +112).  Aligned b64 base + funnel shift.
  const int sA   = ((jg * 2 + 0) * 2 + slot) * 56 + w2 - 3;  // may be -3..892
  const int s4   = sA & ~3;                       // 4-u16 (8B) aligned
  const u32 sh   = (u32)(sA & 3) * 16;            // funnel shift bits
  const int b0   = 8 + s4;                        // +8 = front pad
  const int b1   = b0 + 112;                      // channel jj=1
  // masks: tap k valid iff w2+k-3 in [0,56)
  u32 mk01, mk23, mk45, mk6;
  {
    u32 m[7];
#pragma unroll
    for (int k = 0; k < 7; ++k)
      m[k] = ((unsigned)(w2 + k - 3) < 56u) ? 0xffffu : 0u;
    mk01 = m[0] | (m[1] << 16);
    mk23 = m[2] | (m[3] << 16);
    mk45 = m[4] | (m[5] << 16);
    mk6  = m[6];
  }
  const int xoff0 = (jg * 2 + 0) * 64 + pr;
  const int xoff1 = (jg * 2 + 1) * 64 + pr;

  // staging descriptors (wave roles): wave1 -> Xs, wave2 -> Rs[0:64),
  // wave3 (lane<48) -> Rs[64:112).  Rs chunk c: ch=c/14, s=(c%14)/7, i=c%7.
  long stSrcOff = 0;     // iter-invariant part of source offset (u16 units)
  int  stCh = 0;         // channel index 0..7
  bool stR = false, stX = false;
  {
    if (wave == 1) {
      stX = true; stCh = lane >> 3;
      stSrcOff = n0 + (lane & 7) * 8;
    } else if (wave == 2 || (wave == 3 && lane < 48)) {
      stR = true;
      int c = (wave == 2) ? lane : 64 + lane;
      stCh = c / 14;
      int rem = c - stCh * 14;
      int s = rem / 7, i = rem - s * 7;
      int h2s = ((h_lo + s) + HH - 1) % HH;       // h_lo+s <= 55 always
      stSrcOff = h2s * 56 + i * 8;
    }
  }

  f32x4 acc[4][2];
#pragma unroll
  for (int a = 0; a < 4; ++a)
#pragma unroll
    for (int b = 0; b < 2; ++b) acc[a][b] = (f32x4)0.0f;

  // A-fragment register sets (even/odd iterations) — static indexing only
  bf16x8 aE[8], aO[8];

#define APF(aS, itn) do { const int koff_ = (itn) * 64;                        \
    _Pragma("unroll")                                                          \
    for (int mi = 0; mi < 4; ++mi) {                                           \
      (aS)[mi * 2 + 0] = *(const bf16x8*)(aRowP[mi] + koff_);                  \
      (aS)[mi * 2 + 1] = *(const bf16x8*)(aRowP[mi] + koff_ + 32);             \
    } } while (0)

#define STAGE(RsD, XsD, itn) do {                                              \
    if (stX)                                                                   \
      lds_load16(xbn + (long)((itn) * 8 + stCh) * HW + stSrcOff,               \
                 &XsD[lane * 8]);                                              \
    else if (stR) {                                                            \
      const int jmm_ = ((itn) * 8 + stCh + CC - 1) & (CC - 1);                 \
      lds_load16(t1n + (long)jmm_ * HW + stSrcOff,                             \
                 (wave == 2) ? &RsD[8 + lane * 8] : &RsD[8 + 512 + lane * 8]); \
    } } while (0)

// one channel: 3 ds_read_b64 -> funnel -> masked pack into uint4
#define TAPS(RsS, bofs, xr, d4) do {                                           \
    u64 q0 = *(const u64*)&(RsS)[(bofs)];                                      \
    u64 q1 = *(const u64*)&(RsS)[(bofs) + 4];                                  \
    u64 q2 = *(const u64*)&(RsS)[(bofs) + 8];                                  \
    u64 a_ = (q0 >> sh) | (sh ? (q1 << (64u - sh)) : 0ull);                    \
    u64 b_ = (q1 >> sh) | (sh ? (q2 << (64u - sh)) : 0ull);                    \
    (d4) = make_uint4(((u32)a_) & mk01, ((u32)(a_ >> 32)) & mk23,              \
                      ((u32)b_) & mk45,                                        \
                      (((u32)(b_ >> 32)) & mk6) | ((u32)(xr) << 16));          \
  } while (0)

#define BGEN(RsS, XsS) do {                                                    \
    u16 xr0_ = XsS[xoff0], xr1_ = XsS[xoff1];                                  \
    uint4 d0_, d1_;                                                            \
    TAPS(RsS, b0, xr0_, d0_);                                                  \
    TAPS(RsS, b1, xr1_, d1_);                                                  \
    *(uint4*)&Bs[pr * 64 + (((jg * 2 + 0) ^ swz) * 8)] = d0_;                  \
    *(uint4*)&Bs[pr * 64 + (((jg * 2 + 1) ^ swz) * 8)] = d1_;                  \
  } while (0)

#define MFMA2R(aS) do {                                                        \
    _Pragma("unroll")                                                          \
    for (int kk = 0; kk < 2; ++kk) {                                           \
      const int phys = ((kk * 4 + quad) ^ (lm & 7)) * 8;                       \
      bf16x8 bv[2];                                                            \
      _Pragma("unroll")                                                        \
      for (int ni = 0; ni < 2; ++ni)                                           \
        bv[ni] = *(const bf16x8*)&Bs[(wn * 32 + ni * 16 + lm) * 64 + phys];    \
      _Pragma("unroll")                                                        \
      for (int mi = 0; mi < 4; ++mi)                                           \
        _Pragma("unroll")                                                      \
        for (int ni = 0; ni < 2; ++ni)                                         \
          acc[mi][ni] = __builtin_amdgcn_mfma_f32_16x16x32_bf16(               \
              (aS)[mi * 2 + kk], bv[ni], acc[mi][ni], 0, 0, 0);                \
    } } while (0)

  // ---- prologue: inputs for it=0 (one-time cold drain) ----
  STAGE(Rs0, Xs0, 0);
  APF(aE, 0);
  __syncthreads();

  // ---- main: 32 iterations, 2 barriers each; ALL VMEM issued in MFMA phase ----
  for (int itp = 0; itp < 16; ++itp) {
    const int itE = itp * 2;
    // iteration itE (even): consume Rs0/Xs0/aE
    BGEN(Rs0, Xs0);                // build B(itE) into Bs
    __syncthreads();               // bar_a: no VMEM outstanding -> cheap
    STAGE(Rs1, Xs1, itE + 1);      // issue under MFMA cover
    APF(aO, itE + 1);              // A(itE+1) into other reg set
    MFMA2R(aE);
    __syncthreads();               // bar_b: drains (itE+1) loads, MFMA-covered
    // iteration itE+1 (odd): consume Rs1/Xs1/aO
    BGEN(Rs1, Xs1);
    __syncthreads();
    if (itE + 2 < 32) {
      STAGE(Rs0, Xs0, itE + 2);
      APF(aE, itE + 2);
    }
    MFMA2R(aO);
    __syncthreads();
  }

#undef APF
#undef STAGE
#undef TAPS
#undef BGEN
#undef MFMA2R

  const float s2 = 0.023622783f;                  // 1/sqrt(1792)
  float* Ob = out + (long)nb * CC * HW;
#pragma unroll
  for (int mi = 0; mi < 4; ++mi)
#pragma unroll
    for (int ni = 0; ni < 2; ++ni) {
      int rb = m0 + wm * 64 + mi * 16 + quad * 4;
      int cg = n0 + wn * 32 + ni * 16 + lm;       // < 3136 always (49*64)
#pragma unroll
      for (int r4 = 0; r4 < 4; ++r4)
        Ob[(long)(rb + r4) * HW + cg] = acc[mi][ni][r4] * s2;
    }
}

// ---------------------------------------------------------------------------
// Pipeline: pass1 -> gemm1f -> reduce1 -> gemm2f(-> d_out).  ~101 MB footprint.
// ---------------------------------------------------------------------------
extern "C" void kernel_launch(void* const* d_in, const int* in_sizes, int n_in,
                              void* d_out, int out_size, void* d_ws, size_t ws_size,
                              hipStream_t stream) {
  const float* x   = (const float*)d_in[0];   // (8,256,56,56)
  const float* p1w = (const float*)d_in[1];   // (1,256,56,56)

  char* ws = (char*)d_ws;
  size_t o = 0;
  u16* xb  = (u16*)(ws + o); o += (size_t)NB * CC * HW * 2;          //  12.8 MB
  u16* t1b = (u16*)(ws + o); o += (size_t)NB * CC * HW * 2;          //  12.8 MB
  u16* t7  = (u16*)(ws + o); o += (size_t)NB * CC * CKP * 2;         //   8.4 MB
  float* p1 = (float*)(ws + o); o += (size_t)KS1 * NB * CC * CKP * 4; // 67.1 MB

  pass1<<<NB * CC * HW / 4 / 256, 256, 0, stream>>>(x, p1w, t1b, xb);
  gemm1f<<<NB * KS1 * 2 * 16, 256, 0, stream>>>(xb, t1b, p1);
  reduce1<<<NB * CC * CKP / 8 / 256, 256, 0, stream>>>(p1, t7);
  gemm2f<<<NB * 2 * 49, 256, 0, stream>>>(t7, xb, t1b, (float*)d_out);
}

// Round 14
// 177.459 us; speedup vs baseline: 1.4632x; 1.4632x over previous
//
#include <hip/hip_runtime.h>

typedef unsigned short u16;
typedef unsigned int u32;
typedef unsigned long long u64;
typedef __bf16 bf16x8 __attribute__((ext_vector_type(8)));
typedef float f32x4 __attribute__((ext_vector_type(4)));

#define HH  56
#define WW  56
#define HW  3136      // 56*56
#define CC  256
#define NB  8
#define CKP 2048      // c*7 padded to c*8: channel j's taps = cols j*8..j*8+7
#define KS1 4         // split-K factor GEMM1 (49 iters -> 12/12/12/13)

// round-to-nearest-even fp32 -> bf16 (bit pattern) — for non-hot paths
__device__ __forceinline__ u16 f2bf(float f) {
  unsigned int u = __float_as_uint(f);
  u += 0x7fffu + ((u >> 16) & 1u);
  return (u16)(u >> 16);
}
__device__ __forceinline__ float bf2f(u16 v) {
  return __uint_as_float((unsigned)v << 16);
}

// async global->LDS DMA, 16B per lane; dest = wave-uniform base + lane*16
__device__ __forceinline__ void lds_load16(const void* g, void* l) {
  __builtin_amdgcn_global_load_lds(
      (const __attribute__((address_space(1))) void*)g,
      (__attribute__((address_space(3))) void*)l, 16, 0, 0);
}

// ---------------------------------------------------------------------------
// pass1 (round-6 exact, from the 177.8 µs run): t1b = bf16(p1w * x),
// xb = bf16(x).  Fully coalesced float4 reads.  grid = N*C*HW/4/256 = 6272
// ---------------------------------------------------------------------------
__global__ void pass1(const float* __restrict__ x, const float* __restrict__ p1w,
                      u16* __restrict__ t1b, u16* __restrict__ xb) {
  int i = blockIdx.x * 256 + threadIdx.x;        // over N*C*HW/4
  int cw = i % (CC * HW / 4);                    // p1w broadcast over n
  float4 xv = ((const float4*)x)[i];
  float4 wv = ((const float4*)p1w)[cw];
  uint2 xo = make_uint2((unsigned)f2bf(xv.x) | ((unsigned)f2bf(xv.y) << 16),
                        (unsigned)f2bf(xv.z) | ((unsigned)f2bf(xv.w) << 16));
  ((uint2*)xb)[i] = xo;
  uint2 to = make_uint2((unsigned)f2bf(xv.x * wv.x) | ((unsigned)f2bf(xv.y * wv.y) << 16),
                        (unsigned)f2bf(xv.z * wv.z) | ((unsigned)f2bf(xv.w * wv.w) << 16));
  ((uint2*)t1b)[i] = to;
}

// ---------------------------------------------------------------------------
// gemm1f (R13-exact structure from the 177.8 run; only change: the wrap
// check was dead code — w0t = 8*((it+pc) mod 7) <= 48 so w0t+e < 56 always).
// 4 blocks/CU; VGPR <=128 (no prefetch register sets — proven R11/R17).
// 2-barrier schedule, select-only B-gen, XCD-pinned flat grid.
//   B rows j*8+k (k<7) = masked taps of t2[j]; row j*8+7 = t1[j] (G-row).
// grid = 1024 flat
// ---------------------------------------------------------------------------
__global__ __launch_bounds__(256)
void gemm1f(const u16* __restrict__ A, const u16* __restrict__ t1b,
            float* __restrict__ Cp) {
  __shared__ u16 As[128 * 64];
  __shared__ u16 Bs[128 * 64];

  const int bi = blockIdx.x;
  const int nb = bi & 7;
  const int r  = bi >> 3;          // 0..127
  const int ks = r & 3;
  const int r2 = r >> 2;           // 0..31
  const int m0b = r2 & 1;
  const int n0b = r2 >> 1;         // 0..15

  const int it0 = 49 * ks / KS1, it1 = 49 * (ks + 1) / KS1;
  const u16* Ab  = A   + (long)nb * CC * HW;
  const u16* t1n = t1b + (long)nb * CC * HW;
  const int m0 = m0b * 128, n0 = n0b * 128;
  const int jb = n0b * 16;                        // first channel of tile
  const int t = threadIdx.x;
  const int lane = t & 63, wave = t >> 6;
  const int wm = wave & 1, wn = wave >> 1;        // 2x2 waves, 64x64 each
  const int lm = lane & 15, quad = lane >> 4;

  // B-gen mapping
  const int jl = (t >> 3) & 15, pc = t & 7, hf = t >> 7;   // hf wave-uniform
  const int j  = jb + jl;
  const int jm = (j + CC - 1) & (CC - 1);
  const u16* arow = t1n + (long)j  * HW;
  const u16* wrow = t1n + (long)jm * HW;

  f32x4 acc[4][4];
#pragma unroll
  for (int a = 0; a < 4; ++a)
#pragma unroll
    for (int b = 0; b < 4; ++b) acc[a][b] = (f32x4)0.0f;

  // A staging geometry: 1024 chunks of 16B, 4 per thread, XOR swizzle
  int rowc[4], colc[4];
#pragma unroll
  for (int ci = 0; ci < 4; ++ci) {
    int c = t + ci * 256;
    rowc[ci] = c >> 3;
    colc[ci] = ((c & 7) ^ (rowc[ci] & 7)) * 8;
  }

  for (int it = it0; it < it1; ++it) {
    const int k0 = it * 64;
#pragma unroll
    for (int ci = 0; ci < 4; ++ci)
      lds_load16(Ab + (long)(m0 + rowc[ci]) * HW + k0 + colc[ci],
                 &As[(t + ci * 256) * 8]);

    // ---- B-gen: 8 p-values (p8..p8+7), rows jl*8+k. Pure u16 selects. ----
    {
      const int p8 = k0 + pc * 8;
      __attribute__((aligned(16))) u16 Ar[8];
      __attribute__((aligned(16))) u16 Wd[24];     // window = flat [p8-8, p8+16)
      *(uint4*)Ar = *(const uint4*)&arow[p8];
#pragma unroll
      for (int L = 0; L < 3; ++L) {
        int ad = p8 - 8 + L * 8;
        ad = ad < 0 ? 0 : (ad > HW - 8 ? HW - 8 : ad);  // garbage only at masked idx
        *(uint4*)&Wd[L * 8] = *(const uint4*)&wrow[ad];
      }
      // w0t = 8*((it+pc) mod 7) in {0,8,...,48}; w0t+e <= 55 -> NO wrap.
      const int w0t = p8 % 56;
      if (hf == 0) {                           // k = 0..3
#pragma unroll
        for (int k = 0; k < 4; ++k) {
          __attribute__((aligned(16))) u16 v[8];
#pragma unroll
          for (int e = 0; e < 8; ++e)
            v[e] = ((unsigned)(w0t + e + k - 3) < 56u) ? Wd[e + k + 5] : (u16)0;
          *(uint4*)&Bs[(jl * 8 + k) * 64 + (pc ^ k) * 8] = *(const uint4*)v;
        }
      } else {                                 // k = 4..6 + G-row (slot 7)
#pragma unroll
        for (int k = 4; k < 7; ++k) {
          __attribute__((aligned(16))) u16 v[8];
#pragma unroll
          for (int e = 0; e < 8; ++e)
            v[e] = ((unsigned)(w0t + e + k - 3) < 56u) ? Wd[e + k + 5] : (u16)0;
          *(uint4*)&Bs[(jl * 8 + k) * 64 + (pc ^ k) * 8] = *(const uint4*)v;
        }
        // slot 7 = t1[j] row -> produces G[i][j] in output col j*8+7
        *(uint4*)&Bs[(jl * 8 + 7) * 64 + (pc ^ 7) * 8] = *(const uint4*)Ar;
      }
    }
    __syncthreads();
#pragma unroll
    for (int kk = 0; kk < 2; ++kk) {
      const int phys = ((kk * 4 + quad) ^ (lm & 7)) * 8;
      bf16x8 af[4], bv[4];
#pragma unroll
      for (int mi = 0; mi < 4; ++mi)
        af[mi] = *(const bf16x8*)&As[(wm * 64 + mi * 16 + lm) * 64 + phys];
#pragma unroll
      for (int ni = 0; ni < 4; ++ni)
        bv[ni] = *(const bf16x8*)&Bs[(wn * 64 + ni * 16 + lm) * 64 + phys];
#pragma unroll
      for (int mi = 0; mi < 4; ++mi)
#pragma unroll
        for (int ni = 0; ni < 4; ++ni)
          acc[mi][ni] = __builtin_amdgcn_mfma_f32_16x16x32_bf16(
              af[mi], bv[ni], acc[mi][ni], 0, 0, 0);
    }
    __syncthreads();
  }

  // fp32 partial store; C/D layout: col = lane&15, row = quad*4 + reg
  float* Cb = Cp + ((long)ks * NB + nb) * (long)CC * CKP;
#pragma unroll
  for (int mi = 0; mi < 4; ++mi)
#pragma unroll
    for (int ni = 0; ni < 4; ++ni) {
      int rb = m0 + wm * 64 + mi * 16 + quad * 4;
      int cg = n0 + wn * 64 + ni * 16 + lm;
#pragma unroll
      for (int r4 = 0; r4 < 4; ++r4)
        Cb[(long)(rb + r4) * CKP + cg] = acc[mi][ni][r4];
    }
}

// ---------------------------------------------------------------------------
// reduce1 (round-6 exact, from the 177.8 run): per thread = one j-group
// (8 cols).  Sums KS1 partials, t7[jk] = (G - H_k)/56 (fp32 subtract),
// S7 = sum_k t7[jk] into slot 7.  grid = NB*CC*CKP/8/256 = 2048
// ---------------------------------------------------------------------------
__global__ void reduce1(const float* __restrict__ p1, u16* __restrict__ t7) {
  const int g = blockIdx.x * 256 + threadIdx.x;   // j-group over NB*CC*CKP/8
  const long S = (long)NB * CC * CKP;             // elements per partial
  const long base = (long)g * 8;
  float a[8];
#pragma unroll
  for (int e = 0; e < 8; ++e) a[e] = 0.0f;
#pragma unroll
  for (int ks = 0; ks < KS1; ++ks) {
    float4 lo = *(const float4*)&p1[ks * S + base];
    float4 hi = *(const float4*)&p1[ks * S + base + 4];
    a[0] += lo.x; a[1] += lo.y; a[2] += lo.z; a[3] += lo.w;
    a[4] += hi.x; a[5] += hi.y; a[6] += hi.z; a[7] += hi.w;
  }
  const float s = 1.0f / 56.0f;
  const float G = a[7];
  __attribute__((aligned(16))) u16 o[8];
  float s7 = 0.0f;
#pragma unroll
  for (int k = 0; k < 7; ++k) {
    float v = (G - a[k]) * s;
    s7 += v;
    o[k] = f2bf(v);
  }
  o[7] = f2bf(s7);
  *(uint4*)&t7[base] = *(const uint4*)o;
}

// ---------------------------------------------------------------------------
// gemm2f (R19-exact, best measured 59.3 µs): fused NT GEMM, 128x64 tile,
// BK=64, XCD-pinned.
//   out[i][p] = s2 * ( sum_{j,k<7} t7[i][jk]*tap[j,k,p]  +  S7[i][j]*xb[j][p] )
// Funnel-shift BGEN (3 aligned ds_read_b64 + 2 u64 funnel shifts + 4 AND
// masks per channel, replacing 14 scalar ds_read_u16) + all VMEM issued in
// the MFMA phase (bar_a drains nothing; bar_b drains loads covered by the
// full ds_read+MFMA chain).  As dbuf (47 KB LDS, 3 blocks/CU).  grid = 784
// ---------------------------------------------------------------------------
__global__ __launch_bounds__(256)
void gemm2f(const u16* __restrict__ A, const u16* __restrict__ xb,
            const u16* __restrict__ t1b, float* __restrict__ out) {
  __shared__ u16 As0[128 * 64], As1[128 * 64];    // 16 KB each
  __shared__ u16 Bs[64 * 64];                     //  8 KB
  // [8 pad][8ch][2row][56][8 pad] = 912 u16 each
  __shared__ __attribute__((aligned(16))) u16 Rs0[912], Rs1[912];
  __shared__ __attribute__((aligned(16))) u16 Xs0[512], Xs1[512]; // [8ch][64]

  // flat block index -> (nb | m0b | n0b), nb fastest => XCD-pinned
  const int bi = blockIdx.x;
  const int nb = bi & 7;
  const int r  = bi >> 3;          // 0..97
  const int m0b = r & 1;
  const int n0b = r >> 1;          // 0..48

  const u16* Ab  = A   + (long)nb * CC * CKP;
  const u16* xbn = xb  + (long)nb * CC * HW;
  const u16* t1n = t1b + (long)nb * CC * HW;
  const int m0 = m0b * 128, n0 = n0b * 64;
  const int t = threadIdx.x;
  const int lane = t & 63, wave = t >> 6;
  const int wm = wave & 1, wn = wave >> 1;        // 2(m) x 2(n of 32)
  const int lm = lane & 15, quad = lane >> 4;

  // B-gen read mapping: pr = p-row, jg -> 2 channels per thread per iter
  const int pr = t & 63, jg = t >> 6;
  const int p  = n0 + pr;
  const int h  = p / WW, w = p - h * WW;
  const int w2 = (w + 1) % WW;                    // roll -1 on w
  const int swz = pr & 7;
  const int h_lo = n0 / WW;
  const int slot = h - h_lo;                      // 0 or 1 (64 p span 2 rows)

  // iter-invariant window geometry: channel jj window = Rs u16s [sA, sA+6]
  // (channel jj=1 offset +112).  Aligned b64 base + funnel shift.
  const int sA   = ((jg * 2 + 0) * 2 + slot) * 56 + w2 - 3;  // may be -3..892
  const int s4   = sA & ~3;                       // 4-u16 (8B) aligned
  const u32 sh   = (u32)(sA & 3) * 16;            // funnel shift bits
  const int b0   = 8 + s4;                        // +8 = front pad
  const int b1   = b0 + 112;                      // channel jj=1
  // masks: tap k valid iff w2+k-3 in [0,56)
  u32 mk01, mk23, mk45, mk6;
  {
    u32 m[7];
#pragma unroll
    for (int k = 0; k < 7; ++k)
      m[k] = ((unsigned)(w2 + k - 3) < 56u) ? 0xffffu : 0u;
    mk01 = m[0] | (m[1] << 16);
    mk23 = m[2] | (m[3] << 16);
    mk45 = m[4] | (m[5] << 16);
    mk6  = m[6];
  }
  const int xoff0 = (jg * 2 + 0) * 64 + pr;
  const int xoff1 = (jg * 2 + 1) * 64 + pr;

  // staging descriptors (wave roles): wave1 -> Xs, wave2 -> Rs[0:64),
  // wave3 (lane<48) -> Rs[64:112).  Rs chunk c: ch=c/14, s=(c%14)/7, i=c%7.
  long stSrcOff = 0;     // iter-invariant part of source offset (u16 units)
  int  stCh = 0;         // channel index 0..7
  bool stR = false, stX = false;
  {
    if (wave == 1) {
      stX = true; stCh = lane >> 3;
      stSrcOff = n0 + (lane & 7) * 8;
    } else if (wave == 2 || (wave == 3 && lane < 48)) {
      stR = true;
      int c = (wave == 2) ? lane : 64 + lane;
      stCh = c / 14;
      int rem = c - stCh * 14;
      int s = rem / 7, i = rem - s * 7;
      int h2s = ((h_lo + s) + HH - 1) % HH;       // h_lo+s <= 55 always
      stSrcOff = h2s * 56 + i * 8;
    }
  }

  f32x4 acc[4][2];
#pragma unroll
  for (int a = 0; a < 4; ++a)
#pragma unroll
    for (int b = 0; b < 2; ++b) acc[a][b] = (f32x4)0.0f;

  int rowc[4], colc[4];
#pragma unroll
  for (int ci = 0; ci < 4; ++ci) {
    int c = t + ci * 256;
    rowc[ci] = c >> 3;
    colc[ci] = ((c & 7) ^ (rowc[ci] & 7)) * 8;
  }

#define DMAA(AsD, itn) do { const int k0_ = (itn) * 64;                        \
    _Pragma("unroll")                                                          \
    for (int ci = 0; ci < 4; ++ci)                                             \
      lds_load16(Ab + (long)(m0 + rowc[ci]) * CKP + k0_ + colc[ci],            \
                 &AsD[(t + ci * 256) * 8]); } while (0)

#define STAGE(RsD, XsD, itn) do {                                              \
    if (stX)                                                                   \
      lds_load16(xbn + (long)((itn) * 8 + stCh) * HW + stSrcOff,               \
                 &XsD[lane * 8]);                                              \
    else if (stR) {                                                            \
      const int jmm_ = ((itn) * 8 + stCh + CC - 1) & (CC - 1);                 \
      lds_load16(t1n + (long)jmm_ * HW + stSrcOff,                             \
                 (wave == 2) ? &RsD[8 + lane * 8] : &RsD[8 + 512 + lane * 8]); \
    } } while (0)

// one channel: 3 ds_read_b64 -> funnel -> masked pack into uint4
#define TAPS(RsS, bofs, xr, d4) do {                                           \
    u64 q0 = *(const u64*)&(RsS)[(bofs)];                                      \
    u64 q1 = *(const u64*)&(RsS)[(bofs) + 4];                                  \
    u64 q2 = *(const u64*)&(RsS)[(bofs) + 8];                                  \
    u64 a_ = (q0 >> sh) | (sh ? (q1 << (64u - sh)) : 0ull);                    \
    u64 b_ = (q1 >> sh) | (sh ? (q2 << (64u - sh)) : 0ull);                    \
    (d4) = make_uint4(((u32)a_) & mk01, ((u32)(a_ >> 32)) & mk23,              \
                      ((u32)b_) & mk45,                                        \
                      (((u32)(b_ >> 32)) & mk6) | ((u32)(xr) << 16));          \
  } while (0)

#define BGEN(RsS, XsS) do {                                                    \
    u16 xr0_ = XsS[xoff0], xr1_ = XsS[xoff1];                                  \
    uint4 d0_, d1_;                                                            \
    TAPS(RsS, b0, xr0_, d0_);                                                  \
    TAPS(RsS, b1, xr1_, d1_);                                                  \
    *(uint4*)&Bs[pr * 64 + (((jg * 2 + 0) ^ swz) * 8)] = d0_;                  \
    *(uint4*)&Bs[pr * 64 + (((jg * 2 + 1) ^ swz) * 8)] = d1_;                  \
  } while (0)

#define MFMA2(AsS) do {                                                        \
    _Pragma("unroll")                                                          \
    for (int kk = 0; kk < 2; ++kk) {                                           \
      const int phys = ((kk * 4 + quad) ^ (lm & 7)) * 8;                       \
      bf16x8 af[4], bv[2];                                                     \
      _Pragma("unroll")                                                        \
      for (int mi = 0; mi < 4; ++mi)                                           \
        af[mi] = *(const bf16x8*)&(AsS)[(wm * 64 + mi * 16 + lm) * 64 + phys]; \
      _Pragma("unroll")                                                        \
      for (int ni = 0; ni < 2; ++ni)                                           \
        bv[ni] = *(const bf16x8*)&Bs[(wn * 32 + ni * 16 + lm) * 64 + phys];    \
      _Pragma("unroll")                                                        \
      for (int mi = 0; mi < 4; ++mi)                                           \
        _Pragma("unroll")                                                      \
        for (int ni = 0; ni < 2; ++ni)                                         \
          acc[mi][ni] = __builtin_amdgcn_mfma_f32_16x16x32_bf16(               \
              af[mi], bv[ni], acc[mi][ni], 0, 0, 0);                           \
    } } while (0)

  // ---- prologue: inputs for it=0 (one-time cold drain) ----
  STAGE(Rs0, Xs0, 0);
  DMAA(As0, 0);
  __syncthreads();

  // ---- main: 32 iterations, 2 barriers each; ALL VMEM issued in MFMA phase ----
  for (int itp = 0; itp < 16; ++itp) {
    const int itE = itp * 2;
    // iteration itE (even): consume Rs0/Xs0/As0
    BGEN(Rs0, Xs0);                // build B(itE) into Bs
    __syncthreads();               // bar_a: no VMEM outstanding -> cheap
    DMAA(As1, itE + 1);            // issue under MFMA cover
    STAGE(Rs1, Xs1, itE + 1);
    MFMA2(As0);
    __syncthreads();               // bar_b: drains (itE+1) loads, MFMA-covered
    // iteration itE+1 (odd): consume Rs1/Xs1/As1
    BGEN(Rs1, Xs1);
    __syncthreads();
    if (itE + 2 < 32) {
      DMAA(As0, itE + 2);
      STAGE(Rs0, Xs0, itE + 2);
    }
    MFMA2(As1);
    __syncthreads();
  }

#undef DMAA
#undef STAGE
#undef TAPS
#undef BGEN
#undef MFMA2

  const float s2 = 0.023622783f;                  // 1/sqrt(1792)
  float* Ob = out + (long)nb * CC * HW;
#pragma unroll
  for (int mi = 0; mi < 4; ++mi)
#pragma unroll
    for (int ni = 0; ni < 2; ++ni) {
      int rb = m0 + wm * 64 + mi * 16 + quad * 4;
      int cg = n0 + wn * 32 + ni * 16 + lm;       // < 3136 always (49*64)
#pragma unroll
      for (int r4 = 0; r4 < 4; ++r4)
        Ob[(long)(rb + r4) * HW + cg] = acc[mi][ni][r4] * s2;
    }
}

// ---------------------------------------------------------------------------
// Pipeline: pass1 -> gemm1f -> reduce1 -> gemm2f(-> d_out).  ~101 MB footprint.
// ---------------------------------------------------------------------------
extern "C" void kernel_launch(void* const* d_in, const int* in_sizes, int n_in,
                              void* d_out, int out_size, void* d_ws, size_t ws_size,
                              hipStream_t stream) {
  const float* x   = (const float*)d_in[0];   // (8,256,56,56)
  const float* p1w = (const float*)d_in[1];   // (1,256,56,56)

  char* ws = (char*)d_ws;
  size_t o = 0;
  u16* xb  = (u16*)(ws + o); o += (size_t)NB * CC * HW * 2;          //  12.8 MB
  u16* t1b = (u16*)(ws + o); o += (size_t)NB * CC * HW * 2;          //  12.8 MB
  u16* t7  = (u16*)(ws + o); o += (size_t)NB * CC * CKP * 2;         //   8.4 MB
  float* p1 = (float*)(ws + o); o += (size_t)KS1 * NB * CC * CKP * 4; // 67.1 MB

  pass1<<<NB * CC * HW / 4 / 256, 256, 0, stream>>>(x, p1w, t1b, xb);
  gemm1f<<<NB * KS1 * 2 * 16, 256, 0, stream>>>(xb, t1b, p1);
  reduce1<<<NB * CC * CKP / 8 / 256, 256, 0, stream>>>(p1, t7);
  gemm2f<<<NB * 2 * 49, 256, 0, stream>>>(t7, xb, t1b, (float*)d_out);
}

// Round 17
// 176.131 us; speedup vs baseline: 1.4743x; 1.0075x over previous
//
#include <hip/hip_runtime.h>

typedef unsigned short u16;
typedef unsigned int u32;
typedef unsigned long long u64;
typedef __bf16 bf16x8 __attribute__((ext_vector_type(8)));
typedef float f32x4 __attribute__((ext_vector_type(4)));

#define HH  56
#define WW  56
#define HW  3136      // 56*56
#define CC  256
#define NB  8
#define CKP 2048      // c*7 padded to c*8: channel j's taps = cols j*8..j*8+7
#define KS1 4         // split-K factor GEMM1 (49 iters -> 12/12/12/13)

// round-to-nearest-even fp32 -> bf16 (bit pattern) — for non-hot paths
__device__ __forceinline__ u16 f2bf(float f) {
  unsigned int u = __float_as_uint(f);
  u += 0x7fffu + ((u >> 16) & 1u);
  return (u16)(u >> 16);
}
__device__ __forceinline__ float bf2f(u16 v) {
  return __uint_as_float((unsigned)v << 16);
}

// async global->LDS DMA, 16B per lane; dest = wave-uniform base + lane*16
__device__ __forceinline__ void lds_load16(const void* g, void* l) {
  __builtin_amdgcn_global_load_lds(
      (const __attribute__((address_space(1))) void*)g,
      (__attribute__((address_space(3))) void*)l, 16, 0, 0);
}

// ---------------------------------------------------------------------------
// pass1 (round-6 exact, from the 177.x µs runs): t1b = bf16(p1w * x),
// xb = bf16(x).  Fully coalesced float4 reads.  grid = N*C*HW/4/256 = 6272
// ---------------------------------------------------------------------------
__global__ void pass1(const float* __restrict__ x, const float* __restrict__ p1w,
                      u16* __restrict__ t1b, u16* __restrict__ xb) {
  int i = blockIdx.x * 256 + threadIdx.x;        // over N*C*HW/4
  int cw = i % (CC * HW / 4);                    // p1w broadcast over n
  float4 xv = ((const float4*)x)[i];
  float4 wv = ((const float4*)p1w)[cw];
  uint2 xo = make_uint2((unsigned)f2bf(xv.x) | ((unsigned)f2bf(xv.y) << 16),
                        (unsigned)f2bf(xv.z) | ((unsigned)f2bf(xv.w) << 16));
  ((uint2*)xb)[i] = xo;
  uint2 to = make_uint2((unsigned)f2bf(xv.x * wv.x) | ((unsigned)f2bf(xv.y * wv.y) << 16),
                        (unsigned)f2bf(xv.z * wv.z) | ((unsigned)f2bf(xv.w * wv.w) << 16));
  ((uint2*)t1b)[i] = to;
}

// ---------------------------------------------------------------------------
// gemm1f (R22-exact): R13 structure (4 blocks/CU; VGPR <=128 — no prefetch
// register sets, proven R11/R17) + dead wrap-check removed.
// 2-barrier schedule, select-only B-gen, XCD-pinned flat grid.
//   B rows j*8+k (k<7) = masked taps of t2[j]; row j*8+7 = t1[j] (G-row).
// grid = 1024 flat
// ---------------------------------------------------------------------------
__global__ __launch_bounds__(256)
void gemm1f(const u16* __restrict__ A, const u16* __restrict__ t1b,
            float* __restrict__ Cp) {
  __shared__ u16 As[128 * 64];
  __shared__ u16 Bs[128 * 64];

  const int bi = blockIdx.x;
  const int nb = bi & 7;
  const int r  = bi >> 3;          // 0..127
  const int ks = r & 3;
  const int r2 = r >> 2;           // 0..31
  const int m0b = r2 & 1;
  const int n0b = r2 >> 1;         // 0..15

  const int it0 = 49 * ks / KS1, it1 = 49 * (ks + 1) / KS1;
  const u16* Ab  = A   + (long)nb * CC * HW;
  const u16* t1n = t1b + (long)nb * CC * HW;
  const int m0 = m0b * 128, n0 = n0b * 128;
  const int jb = n0b * 16;                        // first channel of tile
  const int t = threadIdx.x;
  const int lane = t & 63, wave = t >> 6;
  const int wm = wave & 1, wn = wave >> 1;        // 2x2 waves, 64x64 each
  const int lm = lane & 15, quad = lane >> 4;

  // B-gen mapping
  const int jl = (t >> 3) & 15, pc = t & 7, hf = t >> 7;   // hf wave-uniform
  const int j  = jb + jl;
  const int jm = (j + CC - 1) & (CC - 1);
  const u16* arow = t1n + (long)j  * HW;
  const u16* wrow = t1n + (long)jm * HW;

  f32x4 acc[4][4];
#pragma unroll
  for (int a = 0; a < 4; ++a)
#pragma unroll
    for (int b = 0; b < 4; ++b) acc[a][b] = (f32x4)0.0f;

  // A staging geometry: 1024 chunks of 16B, 4 per thread, XOR swizzle
  int rowc[4], colc[4];
#pragma unroll
  for (int ci = 0; ci < 4; ++ci) {
    int c = t + ci * 256;
    rowc[ci] = c >> 3;
    colc[ci] = ((c & 7) ^ (rowc[ci] & 7)) * 8;
  }

  for (int it = it0; it < it1; ++it) {
    const int k0 = it * 64;
#pragma unroll
    for (int ci = 0; ci < 4; ++ci)
      lds_load16(Ab + (long)(m0 + rowc[ci]) * HW + k0 + colc[ci],
                 &As[(t + ci * 256) * 8]);

    // ---- B-gen: 8 p-values (p8..p8+7), rows jl*8+k. Pure u16 selects. ----
    {
      const int p8 = k0 + pc * 8;
      __attribute__((aligned(16))) u16 Ar[8];
      __attribute__((aligned(16))) u16 Wd[24];     // window = flat [p8-8, p8+16)
      *(uint4*)Ar = *(const uint4*)&arow[p8];
#pragma unroll
      for (int L = 0; L < 3; ++L) {
        int ad = p8 - 8 + L * 8;
        ad = ad < 0 ? 0 : (ad > HW - 8 ? HW - 8 : ad);  // garbage only at masked idx
        *(uint4*)&Wd[L * 8] = *(const uint4*)&wrow[ad];
      }
      // w0t = 8*((it+pc) mod 7) in {0,8,...,48}; w0t+e <= 55 -> NO wrap.
      const int w0t = p8 % 56;
      if (hf == 0) {                           // k = 0..3
#pragma unroll
        for (int k = 0; k < 4; ++k) {
          __attribute__((aligned(16))) u16 v[8];
#pragma unroll
          for (int e = 0; e < 8; ++e)
            v[e] = ((unsigned)(w0t + e + k - 3) < 56u) ? Wd[e + k + 5] : (u16)0;
          *(uint4*)&Bs[(jl * 8 + k) * 64 + (pc ^ k) * 8] = *(const uint4*)v;
        }
      } else {                                 // k = 4..6 + G-row (slot 7)
#pragma unroll
        for (int k = 4; k < 7; ++k) {
          __attribute__((aligned(16))) u16 v[8];
#pragma unroll
          for (int e = 0; e < 8; ++e)
            v[e] = ((unsigned)(w0t + e + k - 3) < 56u) ? Wd[e + k + 5] : (u16)0;
          *(uint4*)&Bs[(jl * 8 + k) * 64 + (pc ^ k) * 8] = *(const uint4*)v;
        }
        // slot 7 = t1[j] row -> produces G[i][j] in output col j*8+7
        *(uint4*)&Bs[(jl * 8 + 7) * 64 + (pc ^ 7) * 8] = *(const uint4*)Ar;
      }
    }
    __syncthreads();
#pragma unroll
    for (int kk = 0; kk < 2; ++kk) {
      const int phys = ((kk * 4 + quad) ^ (lm & 7)) * 8;
      bf16x8 af[4], bv[4];
#pragma unroll
      for (int mi = 0; mi < 4; ++mi)
        af[mi] = *(const bf16x8*)&As[(wm * 64 + mi * 16 + lm) * 64 + phys];
#pragma unroll
      for (int ni = 0; ni < 4; ++ni)
        bv[ni] = *(const bf16x8*)&Bs[(wn * 64 + ni * 16 + lm) * 64 + phys];
#pragma unroll
      for (int mi = 0; mi < 4; ++mi)
#pragma unroll
        for (int ni = 0; ni < 4; ++ni)
          acc[mi][ni] = __builtin_amdgcn_mfma_f32_16x16x32_bf16(
              af[mi], bv[ni], acc[mi][ni], 0, 0, 0);
    }
    __syncthreads();
  }

  // fp32 partial store; C/D layout: col = lane&15, row = quad*4 + reg
  float* Cb = Cp + ((long)ks * NB + nb) * (long)CC * CKP;
#pragma unroll
  for (int mi = 0; mi < 4; ++mi)
#pragma unroll
    for (int ni = 0; ni < 4; ++ni) {
      int rb = m0 + wm * 64 + mi * 16 + quad * 4;
      int cg = n0 + wn * 64 + ni * 16 + lm;
#pragma unroll
      for (int r4 = 0; r4 < 4; ++r4)
        Cb[(long)(rb + r4) * CKP + cg] = acc[mi][ni][r4];
    }
}

// ---------------------------------------------------------------------------
// reduce1 (R23: XCD-PINNED — the single change vs R22).  nb = bi&7 so
// t7[nb] (1 MB/batch, L2-fits) is produced on XCD nb, exactly where
// gemm2f's pinned As-DMA blocks read it every iteration.  Cross-run
// evidence: gemm2f measured 59.3-62.2 µs with pinned reduce1 vs 66.0-66.8
// unpinned (same gemm2f binary).  Math identical: sums KS1 partials,
// t7[jk] = (G - H_k)/56 (fp32), S7 in slot 7.  grid = NB * 256 = 2048
// ---------------------------------------------------------------------------
__global__ void reduce1(const float* __restrict__ p1, u16* __restrict__ t7) {
  const int bi = blockIdx.x;
  const int nb = bi & 7;
  const int gg = (bi >> 3) * 256 + threadIdx.x;   // j-group within batch
  const long S = (long)NB * CC * CKP;             // elements per partial
  const long base = (long)nb * CC * CKP + (long)gg * 8;
  float a[8];
#pragma unroll
  for (int e = 0; e < 8; ++e) a[e] = 0.0f;
#pragma unroll
  for (int ks = 0; ks < KS1; ++ks) {
    float4 lo = *(const float4*)&p1[ks * S + base];
    float4 hi = *(const float4*)&p1[ks * S + base + 4];
    a[0] += lo.x; a[1] += lo.y; a[2] += lo.z; a[3] += lo.w;
    a[4] += hi.x; a[5] += hi.y; a[6] += hi.z; a[7] += hi.w;
  }
  const float s = 1.0f / 56.0f;
  const float G = a[7];
  __attribute__((aligned(16))) u16 o[8];
  float s7 = 0.0f;
#pragma unroll
  for (int k = 0; k < 7; ++k) {
    float v = (G - a[k]) * s;
    s7 += v;
    o[k] = f2bf(v);
  }
  o[7] = f2bf(s7);
  *(uint4*)&t7[base] = *(const uint4*)o;
}

// ---------------------------------------------------------------------------
// gemm2f (R19/R22-exact): fused NT GEMM, 128x64 tile, BK=64, XCD-pinned.
//   out[i][p] = s2 * ( sum_{j,k<7} t7[i][jk]*tap[j,k,p]  +  S7[i][j]*xb[j][p] )
// Funnel-shift BGEN (3 aligned ds_read_b64 + 2 u64 funnel shifts + 4 AND
// masks per channel) + all VMEM issued in the MFMA phase (bar_a drains
// nothing; bar_b drains loads covered by the full ds_read+MFMA chain).
// As dbuf (47 KB LDS, 3 blocks/CU).  grid = 784 flat
// ---------------------------------------------------------------------------
__global__ __launch_bounds__(256)
void gemm2f(const u16* __restrict__ A, const u16* __restrict__ xb,
            const u16* __restrict__ t1b, float* __restrict__ out) {
  __shared__ u16 As0[128 * 64], As1[128 * 64];    // 16 KB each
  __shared__ u16 Bs[64 * 64];                     //  8 KB
  // [8 pad][8ch][2row][56][8 pad] = 912 u16 each
  __shared__ __attribute__((aligned(16))) u16 Rs0[912], Rs1[912];
  __shared__ __attribute__((aligned(16))) u16 Xs0[512], Xs1[512]; // [8ch][64]

  // flat block index -> (nb | m0b | n0b), nb fastest => XCD-pinned
  const int bi = blockIdx.x;
  const int nb = bi & 7;
  const int r  = bi >> 3;          // 0..97
  const int m0b = r & 1;
  const int n0b = r >> 1;          // 0..48

  const u16* Ab  = A   + (long)nb * CC * CKP;
  const u16* xbn = xb  + (long)nb * CC * HW;
  const u16* t1n = t1b + (long)nb * CC * HW;
  const int m0 = m0b * 128, n0 = n0b * 64;
  const int t = threadIdx.x;
  const int lane = t & 63, wave = t >> 6;
  const int wm = wave & 1, wn = wave >> 1;        // 2(m) x 2(n of 32)
  const int lm = lane & 15, quad = lane >> 4;

  // B-gen read mapping: pr = p-row, jg -> 2 channels per thread per iter
  const int pr = t & 63, jg = t >> 6;
  const int p  = n0 + pr;
  const int h  = p / WW, w = p - h * WW;
  const int w2 = (w + 1) % WW;                    // roll -1 on w
  const int swz = pr & 7;
  const int h_lo = n0 / WW;
  const int slot = h - h_lo;                      // 0 or 1 (64 p span 2 rows)

  // iter-invariant window geometry: channel jj window = Rs u16s [sA, sA+6]
  // (channel jj=1 offset +112).  Aligned b64 base + funnel shift.
  const int sA   = ((jg * 2 + 0) * 2 + slot) * 56 + w2 - 3;  // may be -3..892
  const int s4   = sA & ~3;                       // 4-u16 (8B) aligned
  const u32 sh   = (u32)(sA & 3) * 16;            // funnel shift bits
  const int b0   = 8 + s4;                        // +8 = front pad
  const int b1   = b0 + 112;                      // channel jj=1
  // masks: tap k valid iff w2+k-3 in [0,56)
  u32 mk01, mk23, mk45, mk6;
  {
    u32 m[7];
#pragma unroll
    for (int k = 0; k < 7; ++k)
      m[k] = ((unsigned)(w2 + k - 3) < 56u) ? 0xffffu : 0u;
    mk01 = m[0] | (m[1] << 16);
    mk23 = m[2] | (m[3] << 16);
    mk45 = m[4] | (m[5] << 16);
    mk6  = m[6];
  }
  const int xoff0 = (jg * 2 + 0) * 64 + pr;
  const int xoff1 = (jg * 2 + 1) * 64 + pr;

  // staging descriptors (wave roles): wave1 -> Xs, wave2 -> Rs[0:64),
  // wave3 (lane<48) -> Rs[64:112).  Rs chunk c: ch=c/14, s=(c%14)/7, i=c%7.
  long stSrcOff = 0;     // iter-invariant part of source offset (u16 units)
  int  stCh = 0;         // channel index 0..7
  bool stR = false, stX = false;
  {
    if (wave == 1) {
      stX = true; stCh = lane >> 3;
      stSrcOff = n0 + (lane & 7) * 8;
    } else if (wave == 2 || (wave == 3 && lane < 48)) {
      stR = true;
      int c = (wave == 2) ? lane : 64 + lane;
      stCh = c / 14;
      int rem = c - stCh * 14;
      int s = rem / 7, i = rem - s * 7;
      int h2s = ((h_lo + s) + HH - 1) % HH;       // h_lo+s <= 55 always
      stSrcOff = h2s * 56 + i * 8;
    }
  }

  f32x4 acc[4][2];
#pragma unroll
  for (int a = 0; a < 4; ++a)
#pragma unroll
    for (int b = 0; b < 2; ++b) acc[a][b] = (f32x4)0.0f;

  int rowc[4], colc[4];
#pragma unroll
  for (int ci = 0; ci < 4; ++ci) {
    int c = t + ci * 256;
    rowc[ci] = c >> 3;
    colc[ci] = ((c & 7) ^ (rowc[ci] & 7)) * 8;
  }

#define DMAA(AsD, itn) do { const int k0_ = (itn) * 64;                        \
    _Pragma("unroll")                                                          \
    for (int ci = 0; ci < 4; ++ci)                                             \
      lds_load16(Ab + (long)(m0 + rowc[ci]) * CKP + k0_ + colc[ci],            \
                 &AsD[(t + ci * 256) * 8]); } while (0)

#define STAGE(RsD, XsD, itn) do {                                              \
    if (stX)                                                                   \
      lds_load16(xbn + (long)((itn) * 8 + stCh) * HW + stSrcOff,               \
                 &XsD[lane * 8]);                                              \
    else if (stR) {                                                            \
      const int jmm_ = ((itn) * 8 + stCh + CC - 1) & (CC - 1);                 \
      lds_load16(t1n + (long)jmm_ * HW + stSrcOff,                             \
                 (wave == 2) ? &RsD[8 + lane * 8] : &RsD[8 + 512 + lane * 8]); \
    } } while (0)

// one channel: 3 ds_read_b64 -> funnel -> masked pack into uint4
#define TAPS(RsS, bofs, xr, d4) do {                                           \
    u64 q0 = *(const u64*)&(RsS)[(bofs)];                                      \
    u64 q1 = *(const u64*)&(RsS)[(bofs) + 4];                                  \
    u64 q2 = *(const u64*)&(RsS)[(bofs) + 8];                                  \
    u64 a_ = (q0 >> sh) | (sh ? (q1 << (64u - sh)) : 0ull);                    \
    u64 b_ = (q1 >> sh) | (sh ? (q2 << (64u - sh)) : 0ull);                    \
    (d4) = make_uint4(((u32)a_) & mk01, ((u32)(a_ >> 32)) & mk23,              \
                      ((u32)b_) & mk45,                                        \
                      (((u32)(b_ >> 32)) & mk6) | ((u32)(xr) << 16));          \
  } while (0)

#define BGEN(RsS, XsS) do {                                                    \
    u16 xr0_ = XsS[xoff0], xr1_ = XsS[xoff1];                                  \
    uint4 d0_, d1_;                                                            \
    TAPS(RsS, b0, xr0_, d0_);                                                  \
    TAPS(RsS, b1, xr1_, d1_);                                                  \
    *(uint4*)&Bs[pr * 64 + (((jg * 2 + 0) ^ swz) * 8)] = d0_;                  \
    *(uint4*)&Bs[pr * 64 + (((jg * 2 + 1) ^ swz) * 8)] = d1_;                  \
  } while (0)

#define MFMA2(AsS) do {                                                        \
    _Pragma("unroll")                                                          \
    for (int kk = 0; kk < 2; ++kk) {                                           \
      const int phys = ((kk * 4 + quad) ^ (lm & 7)) * 8;                       \
      bf16x8 af[4], bv[2];                                                     \
      _Pragma("unroll")                                                        \
      for (int mi = 0; mi < 4; ++mi)                                           \
        af[mi] = *(const bf16x8*)&(AsS)[(wm * 64 + mi * 16 + lm) * 64 + phys]; \
      _Pragma("unroll")                                                        \
      for (int ni = 0; ni < 2; ++ni)                                           \
        bv[ni] = *(const bf16x8*)&Bs[(wn * 32 + ni * 16 + lm) * 64 + phys];    \
      _Pragma("unroll")                                                        \
      for (int mi = 0; mi < 4; ++mi)                                           \
        _Pragma("unroll")                                                      \
        for (int ni = 0; ni < 2; ++ni)                                         \
          acc[mi][ni] = __builtin_amdgcn_mfma_f32_16x16x32_bf16(               \
              af[mi], bv[ni], acc[mi][ni], 0, 0, 0);                           \
    } } while (0)

  // ---- prologue: inputs for it=0 (one-time cold drain) ----
  STAGE(Rs0, Xs0, 0);
  DMAA(As0, 0);
  __syncthreads();

  // ---- main: 32 iterations, 2 barriers each; ALL VMEM issued in MFMA phase ----
  for (int itp = 0; itp < 16; ++itp) {
    const int itE = itp * 2;
    // iteration itE (even): consume Rs0/Xs0/As0
    BGEN(Rs0, Xs0);                // build B(itE) into Bs
    __syncthreads();               // bar_a: no VMEM outstanding -> cheap
    DMAA(As1, itE + 1);            // issue under MFMA cover
    STAGE(Rs1, Xs1, itE + 1);
    MFMA2(As0);
    __syncthreads();               // bar_b: drains (itE+1) loads, MFMA-covered
    // iteration itE+1 (odd): consume Rs1/Xs1/As1
    BGEN(Rs1, Xs1);
    __syncthreads();
    if (itE + 2 < 32) {
      DMAA(As0, itE + 2);
      STAGE(Rs0, Xs0, itE + 2);
    }
    MFMA2(As1);
    __syncthreads();
  }

#undef DMAA
#undef STAGE
#undef TAPS
#undef BGEN
#undef MFMA2

  const float s2 = 0.023622783f;                  // 1/sqrt(1792)
  float* Ob = out + (long)nb * CC * HW;
#pragma unroll
  for (int mi = 0; mi < 4; ++mi)
#pragma unroll
    for (int ni = 0; ni < 2; ++ni) {
      int rb = m0 + wm * 64 + mi * 16 + quad * 4;
      int cg = n0 + wn * 32 + ni * 16 + lm;       // < 3136 always (49*64)
#pragma unroll
      for (int r4 = 0; r4 < 4; ++r4)
        Ob[(long)(rb + r4) * HW + cg] = acc[mi][ni][r4] * s2;
    }
}

// ---------------------------------------------------------------------------
// Pipeline: pass1 -> gemm1f -> reduce1 -> gemm2f(-> d_out).  ~101 MB footprint.
// ---------------------------------------------------------------------------
extern "C" void kernel_launch(void* const* d_in, const int* in_sizes, int n_in,
                              void* d_out, int out_size, void* d_ws, size_t ws_size,
                              hipStream_t stream) {
  const float* x   = (const float*)d_in[0];   // (8,256,56,56)
  const float* p1w = (const float*)d_in[1];   // (1,256,56,56)

  char* ws = (char*)d_ws;
  size_t o = 0;
  u16* xb  = (u16*)(ws + o); o += (size_t)NB * CC * HW * 2;          //  12.8 MB
  u16* t1b = (u16*)(ws + o); o += (size_t)NB * CC * HW * 2;          //  12.8 MB
  u16* t7  = (u16*)(ws + o); o += (size_t)NB * CC * CKP * 2;         //   8.4 MB
  float* p1 = (float*)(ws + o); o += (size_t)KS1 * NB * CC * CKP * 4; // 67.1 MB

  pass1<<<NB * CC * HW / 4 / 256, 256, 0, stream>>>(x, p1w, t1b, xb);
  gemm1f<<<NB * KS1 * 2 * 16, 256, 0, stream>>>(xb, t1b, p1);
  reduce1<<<NB * CC * CKP / 8 / 256, 256, 0, stream>>>(p1, t7);
  gemm2f<<<NB * 2 * 49, 256, 0, stream>>>(t7, xb, t1b, (float*)d_out);
}